// Round 1
// baseline (147.221 us; speedup 1.0000x reference)
//
#include <hip/hip_runtime.h>

// Shapes (fixed by the problem)
#define B_   32
#define F_   64
#define N_   64
#define C_   256
#define L_   16
#define H_   256
#define NPAIR (F_*F_)        // 4096 (i,j) pairs
#define PPB   32             // pairs per block in kernel C
#define TILES (NPAIR/PPB)    // 128

// ---------------------------------------------------------------------------
// Kernel A: y[bn][h] = sum_c src[bn][c] * W1[h][c]
// One block handles 8 rows of src (staged in LDS); thread h walks W1 row h.
// ---------------------------------------------------------------------------
__global__ __launch_bounds__(256) void kA(const float* __restrict__ src,
                                          const float* __restrict__ W1,
                                          float* __restrict__ y) {
    __shared__ float srow[8][C_];          // 8 KB
    const int row0 = blockIdx.x * 8;
    const int tid  = threadIdx.x;          // tid == h
    #pragma unroll
    for (int r = 0; r < 8; ++r)
        srow[r][tid] = src[(row0 + r) * C_ + tid];
    __syncthreads();

    float acc[8] = {0.f,0.f,0.f,0.f,0.f,0.f,0.f,0.f};
    const float4* w1p = (const float4*)(W1 + tid * C_);
    for (int c4 = 0; c4 < C_/4; ++c4) {
        float4 w = w1p[c4];
        #pragma unroll
        for (int r = 0; r < 8; ++r) {
            float4 s = *(const float4*)&srow[r][c4*4];   // LDS broadcast
            acc[r] += s.x*w.x + s.y*w.y + s.z*w.z + s.w*w.w;
        }
    }
    #pragma unroll
    for (int r = 0; r < 8; ++r)
        y[(row0 + r) * H_ + tid] = acc[r];
}

// ---------------------------------------------------------------------------
// Kernel B: coef[i,j,n] = sum_{k<len-1} [spd[k+1]==n] - [spd[k]==n]
// Stored tiled-transposed: coef_tt[tile][n][p], tile=pair>>5, p=pair&31,
// so kernel C reads 32 contiguous floats per (tile,n) -> scalar loads.
// One thread per (pair, n); 64 threads share a pair (uniform branch bound).
// ---------------------------------------------------------------------------
__global__ __launch_bounds__(256) void kB(const int* __restrict__ spd,
                                          const int* __restrict__ spd_len,
                                          float* __restrict__ coef_tt) {
    const int t    = blockIdx.x * 256 + threadIdx.x;   // [0, 4096*64)
    const int pair = t >> 6;
    const int n    = t & 63;
    const int len  = spd_len[pair];
    const int* row = spd + pair * L_;
    int acc = 0;
    for (int k = 0; k + 1 < len; ++k)
        acc += (row[k+1] == n) - (row[k] == n);
    const int tile = pair >> 5, p = pair & 31;
    coef_tt[(tile * 64 + n) * 32 + p] = (float)acc;
}

// ---------------------------------------------------------------------------
// Kernel C: h[b,pair,h] = sum_n coef[pair,n] * y[b,n,h]; PReLU; dot W2.
// Block = (b, tile of 32 pairs). y[b] (64KB) staged in LDS once.
// 32 accumulators/thread -> 32 FMA per LDS read.
// ---------------------------------------------------------------------------
__global__ __launch_bounds__(256) void kC(const float* __restrict__ y,
                                          const float* __restrict__ coef_tt,
                                          const float* __restrict__ W2,
                                          const float* __restrict__ prelu_a,
                                          float* __restrict__ out) {
    __shared__ float yb[N_ * H_];          // 64 KB (reused for reduction)
    const int b    = blockIdx.x / TILES;
    const int tile = blockIdx.x % TILES;
    const int tid  = threadIdx.x;          // tid == h

    // stage y[b] (16384 floats) as float4, coalesced
    const float4* ysrc = (const float4*)(y + b * N_ * H_);
    float4*       ydst = (float4*)yb;
    #pragma unroll
    for (int i = 0; i < 16; ++i)
        ydst[tid + i * 256] = ysrc[tid + i * 256];
    __syncthreads();

    const float* ct = coef_tt + tile * (64 * 32);
    float acc[PPB];
    #pragma unroll
    for (int p = 0; p < PPB; ++p) acc[p] = 0.f;

    for (int n = 0; n < N_; ++n) {
        const float yv = yb[n * H_ + tid];
        const float* cn = ct + n * 32;     // uniform -> s_load
        #pragma unroll
        for (int p = 0; p < PPB; ++p)
            acc[p] += cn[p] * yv;
    }

    __syncthreads();                       // yb reads done; reuse as red[]
    float* red = yb;                       // PPB*4 floats

    const float a   = *prelu_a;
    const float w2h = W2[tid];
    const int lane = tid & 63, wave = tid >> 6;
    #pragma unroll
    for (int p = 0; p < PPB; ++p) {
        float v = acc[p];
        v = (v >= 0.f) ? v : a * v;
        float s = v * w2h;
        #pragma unroll
        for (int off = 32; off > 0; off >>= 1)
            s += __shfl_xor(s, off);
        if (lane == 0) red[p * 4 + wave] = s;
    }
    __syncthreads();
    if (tid < PPB) {
        float s = red[tid*4] + red[tid*4+1] + red[tid*4+2] + red[tid*4+3];
        out[b * NPAIR + tile * PPB + tid] = s;
    }
}

// ---------------------------------------------------------------------------
extern "C" void kernel_launch(void* const* d_in, const int* in_sizes, int n_in,
                              void* d_out, int out_size, void* d_ws, size_t ws_size,
                              hipStream_t stream) {
    const float* src     = (const float*)d_in[0];
    const float* W1      = (const float*)d_in[1];
    const float* W2      = (const float*)d_in[2];
    const float* prelu_a = (const float*)d_in[3];
    const int*   spd     = (const int*)d_in[4];
    const int*   spd_len = (const int*)d_in[5];
    float* out = (float*)d_out;

    float* y       = (float*)d_ws;                 // 2048*256*4 = 2 MB
    float* coef_tt = y + (B_*N_) * H_;             // 4096*64*4  = 1 MB

    kA<<<B_*N_/8, 256, 0, stream>>>(src, W1, y);
    kB<<<NPAIR*N_/256, 256, 0, stream>>>(spd, spd_len, coef_tt);
    kC<<<B_*TILES, 256, 0, stream>>>(y, coef_tt, W2, prelu_a, out);
}

// Round 2
// 36.142 us; speedup vs baseline: 4.0734x; 4.0734x over previous
//
#include <hip/hip_runtime.h>
#include <hip/hip_bf16.h>

// Shapes (fixed by the problem)
#define B_   32
#define F_   64
#define N_   64
#define C_   256
#define L_   16
#define H_   256
#define NPAIR (F_*F_)        // 4096 (i,j) pairs
#define PG_PAIRS 256         // pairs per block in kC2
#define PLANE_BYTES 32768    // one [256h][64n] ushort plane

typedef __attribute__((ext_vector_type(8))) short bf16x8;
typedef __attribute__((ext_vector_type(4))) float f32x4;

static __device__ __forceinline__ unsigned short f2bf_rne(float f) {
    unsigned u = __builtin_bit_cast(unsigned, f);
    u += 0x7FFFu + ((u >> 16) & 1u);      // round-to-nearest-even
    return (unsigned short)(u >> 16);
}
static __device__ __forceinline__ float bf2f(unsigned short h) {
    unsigned u = ((unsigned)h) << 16;
    return __builtin_bit_cast(float, u);
}

// ---------------------------------------------------------------------------
// Kernel A: y[b,n,h] = sum_c src[b,n,c]*W1[h,c]; emit split-bf16, transposed
// to [b][h][n] with XOR swizzle  byte = (h*128 + n*2) ^ ((h&7)<<4)
// (row = h, 128B rows -> G4 swizzle so kC2's ds_read_b128 is conflict-free).
// Block: 8 n-rows of one b; thread = h. n0 multiple of 8 -> the 8 ushorts per
// thread form one aligned 16B chunk; the XOR only relocates the chunk.
// ---------------------------------------------------------------------------
__global__ __launch_bounds__(256) void kA(const float* __restrict__ src,
                                          const float* __restrict__ W1,
                                          unsigned short* __restrict__ yhi,
                                          unsigned short* __restrict__ ylo) {
    __shared__ float srow[8][C_];          // 8 KB
    const int row0 = blockIdx.x * 8;       // global bn
    const int b  = row0 >> 6;
    const int n0 = row0 & 63;
    const int tid = threadIdx.x;           // tid == h
    #pragma unroll
    for (int r = 0; r < 8; ++r)
        srow[r][tid] = src[(row0 + r) * C_ + tid];
    __syncthreads();

    float acc[8] = {0.f,0.f,0.f,0.f,0.f,0.f,0.f,0.f};
    const float4* w1p = (const float4*)(W1 + tid * C_);
    for (int c4 = 0; c4 < C_/4; ++c4) {
        float4 w = w1p[c4];
        #pragma unroll
        for (int r = 0; r < 8; ++r) {
            float4 s = *(const float4*)&srow[r][c4*4];   // LDS broadcast
            acc[r] += s.x*w.x + s.y*w.y + s.z*w.z + s.w*w.w;
        }
    }

    unsigned hi[8], lo[8];
    #pragma unroll
    for (int r = 0; r < 8; ++r) {
        unsigned short h16 = f2bf_rne(acc[r]);
        unsigned short l16 = f2bf_rne(acc[r] - bf2f(h16));
        hi[r] = h16; lo[r] = l16;
    }
    int4 vh, vl;
    vh.x = hi[0] | (hi[1] << 16); vh.y = hi[2] | (hi[3] << 16);
    vh.z = hi[4] | (hi[5] << 16); vh.w = hi[6] | (hi[7] << 16);
    vl.x = lo[0] | (lo[1] << 16); vl.y = lo[2] | (lo[3] << 16);
    vl.z = lo[4] | (lo[5] << 16); vl.w = lo[6] | (lo[7] << 16);

    const unsigned byteoff = ((unsigned)(tid * 128 + n0 * 2)) ^ ((unsigned)(tid & 7) << 4);
    *(int4*)((char*)yhi + (size_t)b * PLANE_BYTES + byteoff) = vh;
    *(int4*)((char*)ylo + (size_t)b * PLANE_BYTES + byteoff) = vl;
}

// ---------------------------------------------------------------------------
// Kernel B: coef[pair,n] (integers in [-15,15], exact in bf16), stored as
// swizzled bf16 rows: byte = pair*128 + ((n*2) ^ ((pair&7)<<4)).
// ---------------------------------------------------------------------------
__global__ __launch_bounds__(256) void kB(const int* __restrict__ spd,
                                          const int* __restrict__ spd_len,
                                          unsigned short* __restrict__ coef) {
    const int t    = blockIdx.x * 256 + threadIdx.x;   // [0, 4096*64)
    const int pair = t >> 6;
    const int n    = t & 63;
    const int len  = spd_len[pair];
    const int* row = spd + pair * L_;
    int acc = 0;
    for (int k = 0; k + 1 < len; ++k)
        acc += (row[k+1] == n) - (row[k] == n);
    const unsigned byteoff = (unsigned)pair * 128u +
                             (((unsigned)(n * 2)) ^ ((unsigned)(pair & 7) << 4));
    *(unsigned short*)((char*)coef + byteoff) = f2bf_rne((float)acc);
}

// ---------------------------------------------------------------------------
// Kernel C2: MFMA contraction + fused PReLU + W2-dot.
// Block = (b, 256-pair group). 4 waves: wave w -> ps=w>>1 (128 pairs),
// hh=w&1 (128 h). y_b hi/lo planes staged to LDS (64KB, layout pre-swizzled
// in global -> linear copy). B-frags persistent in VGPRs (8 ntiles x 2 ks x
// hi/lo). Loop 8 pair-tiles: A-frags straight from global (L2-hot), 32 MFMA,
// epilogue PReLU * W2 -> 16-lane shuffle reduce -> LDS partials -> out.
// MFMA D layout: pair = (lane>>4)*4 + reg, h = lane&15 (+16*ntile).
// ---------------------------------------------------------------------------
__global__ __launch_bounds__(256, 2) void kC2(const unsigned short* __restrict__ yhi_g,
                                              const unsigned short* __restrict__ ylo_g,
                                              const unsigned short* __restrict__ coef,
                                              const float* __restrict__ W2,
                                              const float* __restrict__ prelu_a,
                                              float* __restrict__ out) {
    __shared__ char  ylds[2 * PLANE_BYTES];   // hi plane then lo plane, 64 KB
    __shared__ float red[2][PG_PAIRS];        // per-h-half partials, 2 KB

    const int b   = blockIdx.x >> 4;
    const int pg  = blockIdx.x & 15;
    const int tid = threadIdx.x;

    // ---- stage y_b hi/lo (linear copy; swizzle already applied in global)
    {
        const int4* srch = (const int4*)((const char*)yhi_g + (size_t)b * PLANE_BYTES);
        const int4* srcl = (const int4*)((const char*)ylo_g + (size_t)b * PLANE_BYTES);
        int4* dst = (int4*)ylds;
        #pragma unroll
        for (int i = 0; i < 8; ++i) dst[i * 256 + tid]        = srch[i * 256 + tid];
        #pragma unroll
        for (int i = 0; i < 8; ++i) dst[2048 + i * 256 + tid] = srcl[i * 256 + tid];
    }
    __syncthreads();

    const int lane = tid & 63, w = tid >> 6;
    const int ps = w >> 1, hh = w & 1;
    const int l15 = lane & 15, lg = lane >> 4;

    // ---- persistent B fragments: B[k=n][col=h], lane: h = l15, k = lg*8+j
    bf16x8 bh[8][2], bl[8][2];
    #pragma unroll
    for (int nt = 0; nt < 8; ++nt) {
        const int h = hh * 128 + nt * 16 + l15;
        #pragma unroll
        for (int ks = 0; ks < 2; ++ks) {
            const unsigned nb  = (unsigned)(lg * 16 + ks * 64);
            const unsigned off = ((unsigned)(h * 128) + nb) ^ ((unsigned)(h & 7) << 4);
            bh[nt][ks] = *(const bf16x8*)(ylds + off);
            bl[nt][ks] = *(const bf16x8*)(ylds + PLANE_BYTES + off);
        }
    }

    float w2v[8];
    #pragma unroll
    for (int nt = 0; nt < 8; ++nt) w2v[nt] = W2[hh * 128 + nt * 16 + l15];
    const float a = *prelu_a;
    const int pairbase_blk = pg * PG_PAIRS;

    for (int pt = 0; pt < 8; ++pt) {
        const int prow0 = pairbase_blk + ps * 128 + pt * 16;

        // A fragments from global: A[row=pair][k=n], lane: pair = l15, k = lg*8+j
        bf16x8 af[2];
        #pragma unroll
        for (int ks = 0; ks < 2; ++ks) {
            const int pair = prow0 + l15;
            const unsigned nb  = (unsigned)(lg * 16 + ks * 64);
            const unsigned off = (unsigned)pair * 128u + (nb ^ ((unsigned)(pair & 7) << 4));
            af[ks] = *(const bf16x8*)((const char*)coef + off);
        }

        f32x4 acc[8];
        #pragma unroll
        for (int nt = 0; nt < 8; ++nt) acc[nt] = (f32x4){0.f, 0.f, 0.f, 0.f};
        #pragma unroll
        for (int ks = 0; ks < 2; ++ks)
            #pragma unroll
            for (int nt = 0; nt < 8; ++nt) {
                acc[nt] = __builtin_amdgcn_mfma_f32_16x16x32_bf16(af[ks], bh[nt][ks], acc[nt], 0, 0, 0);
                acc[nt] = __builtin_amdgcn_mfma_f32_16x16x32_bf16(af[ks], bl[nt][ks], acc[nt], 0, 0, 0);
            }

        // epilogue: PReLU, * W2[h], sum over this wave's 128 h
        float s[4] = {0.f, 0.f, 0.f, 0.f};
        #pragma unroll
        for (int nt = 0; nt < 8; ++nt)
            #pragma unroll
            for (int r = 0; r < 4; ++r) {
                float v = acc[nt][r];
                v = fmaxf(v, 0.f) + a * fminf(v, 0.f);
                s[r] += v * w2v[nt];
            }
        #pragma unroll
        for (int m = 1; m < 16; m <<= 1)
            #pragma unroll
            for (int r = 0; r < 4; ++r) s[r] += __shfl_xor(s[r], m);

        if (l15 == 0) {
            #pragma unroll
            for (int r = 0; r < 4; ++r)
                red[hh][ps * 128 + pt * 16 + lg * 4 + r] = s[r];
        }
    }
    __syncthreads();
    out[b * NPAIR + pairbase_blk + tid] = red[0][tid] + red[1][tid];
}

// ---------------------------------------------------------------------------
extern "C" void kernel_launch(void* const* d_in, const int* in_sizes, int n_in,
                              void* d_out, int out_size, void* d_ws, size_t ws_size,
                              hipStream_t stream) {
    const float* src     = (const float*)d_in[0];
    const float* W1      = (const float*)d_in[1];
    const float* W2      = (const float*)d_in[2];
    const float* prelu_a = (const float*)d_in[3];
    const int*   spd     = (const int*)d_in[4];
    const int*   spd_len = (const int*)d_in[5];
    float* out = (float*)d_out;

    char* ws = (char*)d_ws;
    unsigned short* yhi  = (unsigned short*)(ws);                    // 1 MB
    unsigned short* ylo  = (unsigned short*)(ws + (size_t)B_ * PLANE_BYTES);  // 1 MB
    unsigned short* coef = (unsigned short*)(ws + (size_t)2 * B_ * PLANE_BYTES); // 512 KB

    kA<<<B_ * N_ / 8, 256, 0, stream>>>(src, W1, yhi, ylo);
    kB<<<NPAIR * N_ / 256, 256, 0, stream>>>(spd, spd_len, coef);
    kC2<<<B_ * 16, 256, 0, stream>>>(yhi, ylo, coef, W2, prelu_a, out);
}

// Round 3
// 34.851 us; speedup vs baseline: 4.2243x; 1.0370x over previous
//
#include <hip/hip_runtime.h>

// Shapes (fixed by the problem)
#define B_   32
#define F_   64
#define N_   64
#define C_   256
#define L_   16
#define H_   256
#define NPAIR (F_*F_)        // 4096 (i,j) pairs
#define PG_PAIRS 256         // pairs per block in kC3
#define PLANE_BYTES 32768    // one [256h][64n] fp16 plane

typedef __attribute__((ext_vector_type(8))) short     bf16x8;
typedef __attribute__((ext_vector_type(8))) _Float16  f16x8;
typedef __attribute__((ext_vector_type(4))) float     f32x4;
typedef __attribute__((ext_vector_type(4))) unsigned short u16x4;

static __device__ __forceinline__ unsigned short f2bf_rne(float f) {
    unsigned u = __builtin_bit_cast(unsigned, f);
    u += 0x7FFFu + ((u >> 16) & 1u);      // round-to-nearest-even
    return (unsigned short)(u >> 16);
}
static __device__ __forceinline__ float bf2f(unsigned short h) {
    unsigned u = ((unsigned)h) << 16;
    return __builtin_bit_cast(float, u);
}
static __device__ __forceinline__ unsigned short f2h(float f) {
    return __builtin_bit_cast(unsigned short, (_Float16)f);   // v_cvt_f16_f32 (RNE)
}

// ---------------------------------------------------------------------------
// kPrep (fused): [blocks 0..511]   src  -> sh/sl   split-bf16 (float4/thread)
//                [blocks 512..575] W1   -> wh/wl   split-bf16
//                [blocks 576..1599] spd -> coef    fp16, swizzled rows
//                  coef byte = pair*128 + ((n*2) ^ ((pair&7)<<4))
// ---------------------------------------------------------------------------
__global__ __launch_bounds__(256) void kPrep(const float* __restrict__ src,
                                             const float* __restrict__ W1,
                                             const int* __restrict__ spd,
                                             const int* __restrict__ spd_len,
                                             unsigned short* __restrict__ sh,
                                             unsigned short* __restrict__ sl,
                                             unsigned short* __restrict__ wh,
                                             unsigned short* __restrict__ wl,
                                             unsigned short* __restrict__ coef) {
    const int bid = blockIdx.x;
    if (bid < 576) {
        const bool isw = (bid >= 512);
        const float* in        = isw ? W1 : src;
        unsigned short* oh     = isw ? wh : sh;
        unsigned short* ol     = isw ? wl : sl;
        const int t = (isw ? (bid - 512) : bid) * 256 + threadIdx.x;
        float4 v = ((const float4*)in)[t];
        float c[4] = {v.x, v.y, v.z, v.w};
        u16x4 hv, lv;
        #pragma unroll
        for (int i = 0; i < 4; ++i) {
            unsigned short hb = f2bf_rne(c[i]);
            hv[i] = hb;
            lv[i] = f2bf_rne(c[i] - bf2f(hb));
        }
        ((u16x4*)oh)[t] = hv;
        ((u16x4*)ol)[t] = lv;
    } else {
        const int t    = (bid - 576) * 256 + threadIdx.x;   // [0, 4096*64)
        const int pair = t >> 6;
        const int n    = t & 63;
        const int len  = spd_len[pair];
        const int* row = spd + pair * L_;
        int acc = 0;
        for (int k = 0; k + 1 < len; ++k)
            acc += (row[k+1] == n) - (row[k] == n);
        const unsigned off = (unsigned)pair * 128u +
                             (((unsigned)(n * 2)) ^ ((unsigned)(pair & 7) << 4));
        *(unsigned short*)((char*)coef + off) = f2h((float)acc);  // exact, |acc|<=15
    }
}

// ---------------------------------------------------------------------------
// kA (MFMA): y[b][h][n] (fp16, swizzled byte = h*128 + ((n*2)^((h&7)<<4)))
//   y = W1 * src^T  via 3-pass split-bf16 (hi*hi + hi*lo + lo*hi; ll dropped).
// Block: one 16-wide bn strip, 4 waves x 4 h-tiles. Grid 128.
// A-frag (W1): row=h=l15+16*ht, k=c=lg*8+j.  B-frag (src): col=bn=l15, k=c.
// D: col(l15)=bn, row(lg*4+r)=h-sub.
// ---------------------------------------------------------------------------
__global__ __launch_bounds__(256) void kA(const unsigned short* __restrict__ wh,
                                          const unsigned short* __restrict__ wl,
                                          const unsigned short* __restrict__ sh,
                                          const unsigned short* __restrict__ sl,
                                          unsigned short* __restrict__ y) {
    const int tid = threadIdx.x, lane = tid & 63, w = tid >> 6;
    const int l15 = lane & 15, lg = lane >> 4;
    const int bn0 = blockIdx.x * 16;
    const int bnl = bn0 + l15;

    f32x4 acc[4];
    #pragma unroll
    for (int t = 0; t < 4; ++t) acc[t] = (f32x4){0.f, 0.f, 0.f, 0.f};

    #pragma unroll
    for (int kc = 0; kc < 8; ++kc) {
        const int koff = kc * 32 + lg * 8;
        bf16x8 bh = *(const bf16x8*)(sh + bnl * C_ + koff);
        bf16x8 bl = *(const bf16x8*)(sl + bnl * C_ + koff);
        #pragma unroll
        for (int t = 0; t < 4; ++t) {
            const int h = (w * 4 + t) * 16 + l15;
            bf16x8 ah = *(const bf16x8*)(wh + h * C_ + koff);
            bf16x8 al = *(const bf16x8*)(wl + h * C_ + koff);
            acc[t] = __builtin_amdgcn_mfma_f32_16x16x32_bf16(ah, bh, acc[t], 0, 0, 0);
            acc[t] = __builtin_amdgcn_mfma_f32_16x16x32_bf16(ah, bl, acc[t], 0, 0, 0);
            acc[t] = __builtin_amdgcn_mfma_f32_16x16x32_bf16(al, bh, acc[t], 0, 0, 0);
        }
    }

    const int b = bn0 >> 6;
    const int n = (bn0 & 63) + l15;
    char* plane = (char*)y + (size_t)b * PLANE_BYTES;
    #pragma unroll
    for (int t = 0; t < 4; ++t)
        #pragma unroll
        for (int r = 0; r < 4; ++r) {
            const int h = (w * 4 + t) * 16 + lg * 4 + r;
            const unsigned off = (unsigned)(h * 128) +
                                 (((unsigned)(n * 2)) ^ ((unsigned)(h & 7) << 4));
            *(unsigned short*)(plane + off) = f2h(acc[t][r]);
        }
}

// ---------------------------------------------------------------------------
// kC3: fp16 MFMA contraction + fused PReLU + W2-dot.
// Block = (b, 256-pair group). 4 waves: ps=w>>1 (128 pairs), hh=w&1 (128 h).
// y_b plane staged in LDS (32 KB, swizzle pre-applied -> linear copy).
// B-frags persistent (8 nt x 2 ks). 8 pair-tiles x 16 MFMA + epilogue.
// ---------------------------------------------------------------------------
__global__ __launch_bounds__(256, 3) void kC3(const unsigned short* __restrict__ y,
                                              const unsigned short* __restrict__ coef,
                                              const float* __restrict__ W2,
                                              const float* __restrict__ prelu_a,
                                              float* __restrict__ out) {
    __shared__ char  ylds[PLANE_BYTES];       // 32 KB
    __shared__ float red[2][PG_PAIRS];        // 2 KB

    const int b   = blockIdx.x >> 4;
    const int pg  = blockIdx.x & 15;
    const int tid = threadIdx.x;

    {   // stage y_b (linear copy; swizzle already applied in global)
        const int4* src4 = (const int4*)((const char*)y + (size_t)b * PLANE_BYTES);
        int4* dst = (int4*)ylds;
        #pragma unroll
        for (int i = 0; i < 8; ++i) dst[i * 256 + tid] = src4[i * 256 + tid];
    }
    __syncthreads();

    const int lane = tid & 63, w = tid >> 6;
    const int ps = w >> 1, hh = w & 1;
    const int l15 = lane & 15, lg = lane >> 4;

    // persistent B fragments: B[k=n][col=h], lane: h=l15(+16nt), k=lg*8+j(+32ks)
    f16x8 bfrag[8][2];
    #pragma unroll
    for (int nt = 0; nt < 8; ++nt) {
        const int h = hh * 128 + nt * 16 + l15;
        #pragma unroll
        for (int ks = 0; ks < 2; ++ks) {
            const unsigned nb  = (unsigned)(lg * 16 + ks * 64);
            const unsigned off = ((unsigned)(h * 128) + nb) ^ ((unsigned)(h & 7) << 4);
            bfrag[nt][ks] = __builtin_bit_cast(f16x8, *(const bf16x8*)(ylds + off));
        }
    }

    float w2v[8];
    #pragma unroll
    for (int nt = 0; nt < 8; ++nt) w2v[nt] = W2[hh * 128 + nt * 16 + l15];
    const float a = *prelu_a;
    const int pairbase_blk = pg * PG_PAIRS;

    for (int pt = 0; pt < 8; ++pt) {
        const int prow0 = pairbase_blk + ps * 128 + pt * 16;

        f16x8 af[2];
        #pragma unroll
        for (int ks = 0; ks < 2; ++ks) {
            const int pair = prow0 + l15;
            const unsigned nb  = (unsigned)(lg * 16 + ks * 64);
            const unsigned off = (unsigned)pair * 128u + (nb ^ ((unsigned)(pair & 7) << 4));
            af[ks] = __builtin_bit_cast(f16x8, *(const bf16x8*)((const char*)coef + off));
        }

        f32x4 acc[8];
        #pragma unroll
        for (int nt = 0; nt < 8; ++nt) acc[nt] = (f32x4){0.f, 0.f, 0.f, 0.f};
        #pragma unroll
        for (int ks = 0; ks < 2; ++ks)
            #pragma unroll
            for (int nt = 0; nt < 8; ++nt)
                acc[nt] = __builtin_amdgcn_mfma_f32_16x16x32_f16(af[ks], bfrag[nt][ks], acc[nt], 0, 0, 0);

        // epilogue: PReLU, * W2[h], sum over this wave's 128 h
        float s[4] = {0.f, 0.f, 0.f, 0.f};
        #pragma unroll
        for (int nt = 0; nt < 8; ++nt)
            #pragma unroll
            for (int r = 0; r < 4; ++r) {
                float v = acc[nt][r];
                v = fmaxf(v, 0.f) + a * fminf(v, 0.f);
                s[r] += v * w2v[nt];
            }
        #pragma unroll
        for (int m = 1; m < 16; m <<= 1)
            #pragma unroll
            for (int r = 0; r < 4; ++r) s[r] += __shfl_xor(s[r], m);

        if (l15 == 0) {
            #pragma unroll
            for (int r = 0; r < 4; ++r)
                red[hh][ps * 128 + pt * 16 + lg * 4 + r] = s[r];
        }
    }
    __syncthreads();
    out[b * NPAIR + pairbase_blk + tid] = red[0][tid] + red[1][tid];
}

// ---------------------------------------------------------------------------
extern "C" void kernel_launch(void* const* d_in, const int* in_sizes, int n_in,
                              void* d_out, int out_size, void* d_ws, size_t ws_size,
                              hipStream_t stream) {
    const float* src     = (const float*)d_in[0];
    const float* W1      = (const float*)d_in[1];
    const float* W2      = (const float*)d_in[2];
    const float* prelu_a = (const float*)d_in[3];
    const int*   spd     = (const int*)d_in[4];
    const int*   spd_len = (const int*)d_in[5];
    float* out = (float*)d_out;

    unsigned short* sh   = (unsigned short*)d_ws;          // 524288 (1 MB)
    unsigned short* sl   = sh + 524288;                    // 1 MB
    unsigned short* wh   = sl + 524288;                    // 128 KB
    unsigned short* wl   = wh + 65536;                     // 128 KB
    unsigned short* yg   = wl + 65536;                     // 1 MB (32 planes)
    unsigned short* coef = yg + 524288;                    // 512 KB

    kPrep<<<1600, 256, 0, stream>>>(src, W1, spd, spd_len, sh, sl, wh, wl, coef);
    kA  <<<128,  256, 0, stream>>>(wh, wl, sh, sl, yg);
    kC3 <<<B_ * 16, 256, 0, stream>>>(yg, coef, W2, prelu_a, out);
}

// Round 4
// 28.298 us; speedup vs baseline: 5.2026x; 1.2316x over previous
//
#include <hip/hip_runtime.h>

// Shapes (fixed by the problem)
#define B_   32
#define F_   64
#define N_   64
#define C_   256
#define L_   16
#define H_   256
#define NPAIR (F_*F_)        // 4096 (i,j) pairs
#define PG_PAIRS 256         // pairs per block in kC3
#define PLANE_BYTES 32768    // one [256h][64n] fp16 plane

typedef __attribute__((ext_vector_type(8))) short     bf16x8;
typedef __attribute__((ext_vector_type(8))) _Float16  f16x8;
typedef __attribute__((ext_vector_type(4))) float     f32x4;

static __device__ __forceinline__ unsigned short f2bf_rne(float f) {
    unsigned u = __builtin_bit_cast(unsigned, f);
    u += 0x7FFFu + ((u >> 16) & 1u);      // round-to-nearest-even
    return (unsigned short)(u >> 16);
}
static __device__ __forceinline__ float bf2f(unsigned short h) {
    unsigned u = ((unsigned)h) << 16;
    return __builtin_bit_cast(float, u);
}
static __device__ __forceinline__ unsigned short f2h(float f) {
    return __builtin_bit_cast(unsigned short, (_Float16)f);   // v_cvt_f16_f32 (RNE)
}

// ---------------------------------------------------------------------------
// K1: y[b][h][n] (fp16, swizzled byte = h*128 + ((n*2)^((h&7)<<4)))
//   y = W1 * src^T via 3-pass split-bf16, with the fp32->split-bf16 conversion
//   done IN-REGISTER from the raw inputs (no prep kernel, no staging buffers).
// Grid 512: block = (bn-strip of 16) x (h-quarter of 64); wave = 16h x 16bn.
// A-frag (W1): row=h=l15, k=c=lg*8+j.  B-frag (src): col=bn=l15, k=c.
// D: col(l15)=bn, row(lg*4+r)=h-sub.
// Tail: build coef (fp16, swizzled) for 8 pairs/block.
// ---------------------------------------------------------------------------
__global__ __launch_bounds__(256) void k1(const float* __restrict__ src,
                                          const float* __restrict__ W1,
                                          const int* __restrict__ spd,
                                          const int* __restrict__ spd_len,
                                          unsigned short* __restrict__ y,
                                          unsigned short* __restrict__ coef) {
    const int tid = threadIdx.x, lane = tid & 63, w = tid >> 6;
    const int l15 = lane & 15, lg = lane >> 4;
    const int strip = blockIdx.x >> 2;        // 0..127
    const int hq    = blockIdx.x & 3;         // 0..3
    const int bn0   = strip * 16;
    const int htile = hq * 64 + w * 16;
    const int bnl   = bn0 + l15;
    const int hA    = htile + l15;

    f32x4 acc = (f32x4){0.f, 0.f, 0.f, 0.f};

    #pragma unroll
    for (int kc = 0; kc < 8; ++kc) {
        const int koff = kc * 32 + lg * 8;
        float4 a0 = *(const float4*)(W1  + hA  * C_ + koff);
        float4 a1 = *(const float4*)(W1  + hA  * C_ + koff + 4);
        float4 b0 = *(const float4*)(src + bnl * C_ + koff);
        float4 b1 = *(const float4*)(src + bnl * C_ + koff + 4);
        float av[8] = {a0.x,a0.y,a0.z,a0.w,a1.x,a1.y,a1.z,a1.w};
        float bv[8] = {b0.x,b0.y,b0.z,b0.w,b1.x,b1.y,b1.z,b1.w};
        bf16x8 ah, al, bh, bl;
        #pragma unroll
        for (int j = 0; j < 8; ++j) {
            unsigned short hb = f2bf_rne(av[j]);
            ah[j] = (short)hb;
            al[j] = (short)f2bf_rne(av[j] - bf2f(hb));
            unsigned short hb2 = f2bf_rne(bv[j]);
            bh[j] = (short)hb2;
            bl[j] = (short)f2bf_rne(bv[j] - bf2f(hb2));
        }
        acc = __builtin_amdgcn_mfma_f32_16x16x32_bf16(ah, bh, acc, 0, 0, 0);
        acc = __builtin_amdgcn_mfma_f32_16x16x32_bf16(ah, bl, acc, 0, 0, 0);
        acc = __builtin_amdgcn_mfma_f32_16x16x32_bf16(al, bh, acc, 0, 0, 0);
    }

    // store y tile (fp16, swizzled)
    {
        const int b = bn0 >> 6;
        const int n = (bn0 & 63) + l15;
        char* plane = (char*)y + (size_t)b * PLANE_BYTES;
        #pragma unroll
        for (int r = 0; r < 4; ++r) {
            const int h = htile + lg * 4 + r;
            const unsigned off = (unsigned)(h * 128) +
                                 (((unsigned)(n * 2)) ^ ((unsigned)(h & 7) << 4));
            *(unsigned short*)(plane + off) = f2h(acc[r]);
        }
    }

    // coef build: pairs [blockIdx*8, +8), 512 entries, 2 per thread
    #pragma unroll
    for (int rep = 0; rep < 2; ++rep) {
        const int e    = rep * 256 + tid;             // 0..511
        const int pair = blockIdx.x * 8 + (e >> 6);
        const int n    = e & 63;
        const int len  = spd_len[pair];
        const int* row = spd + pair * L_;
        int a = 0;
        for (int k = 0; k + 1 < len; ++k)
            a += (row[k+1] == n) - (row[k] == n);
        const unsigned off = (unsigned)pair * 128u +
                             (((unsigned)(n * 2)) ^ ((unsigned)(pair & 7) << 4));
        *(unsigned short*)((char*)coef + off) = f2h((float)a);  // exact, |a|<=15
    }
}

// ---------------------------------------------------------------------------
// K2: fp16 MFMA contraction + fused PReLU + W2-dot. (unchanged from round 3)
// Block = (b, 256-pair group). 4 waves: ps=w>>1 (128 pairs), hh=w&1 (128 h).
// y_b plane staged in LDS (32 KB, swizzle pre-applied -> linear copy).
// B-frags persistent (8 nt x 2 ks). 8 pair-tiles x 16 MFMA + epilogue.
// ---------------------------------------------------------------------------
__global__ __launch_bounds__(256, 3) void k2(const unsigned short* __restrict__ y,
                                             const unsigned short* __restrict__ coef,
                                             const float* __restrict__ W2,
                                             const float* __restrict__ prelu_a,
                                             float* __restrict__ out) {
    __shared__ char  ylds[PLANE_BYTES];       // 32 KB
    __shared__ float red[2][PG_PAIRS];        // 2 KB

    const int b   = blockIdx.x >> 4;
    const int pg  = blockIdx.x & 15;
    const int tid = threadIdx.x;

    {   // stage y_b (linear copy; swizzle already applied in global)
        const int4* src4 = (const int4*)((const char*)y + (size_t)b * PLANE_BYTES);
        int4* dst = (int4*)ylds;
        #pragma unroll
        for (int i = 0; i < 8; ++i) dst[i * 256 + tid] = src4[i * 256 + tid];
    }
    __syncthreads();

    const int lane = tid & 63, w = tid >> 6;
    const int ps = w >> 1, hh = w & 1;
    const int l15 = lane & 15, lg = lane >> 4;

    // persistent B fragments: B[k=n][col=h], lane: h=l15(+16nt), k=lg*8+j(+32ks)
    f16x8 bfrag[8][2];
    #pragma unroll
    for (int nt = 0; nt < 8; ++nt) {
        const int h = hh * 128 + nt * 16 + l15;
        #pragma unroll
        for (int ks = 0; ks < 2; ++ks) {
            const unsigned nb  = (unsigned)(lg * 16 + ks * 64);
            const unsigned off = ((unsigned)(h * 128) + nb) ^ ((unsigned)(h & 7) << 4);
            bfrag[nt][ks] = __builtin_bit_cast(f16x8, *(const bf16x8*)(ylds + off));
        }
    }

    float w2v[8];
    #pragma unroll
    for (int nt = 0; nt < 8; ++nt) w2v[nt] = W2[hh * 128 + nt * 16 + l15];
    const float a = *prelu_a;
    const int pairbase_blk = pg * PG_PAIRS;

    for (int pt = 0; pt < 8; ++pt) {
        const int prow0 = pairbase_blk + ps * 128 + pt * 16;

        f16x8 af[2];
        #pragma unroll
        for (int ks = 0; ks < 2; ++ks) {
            const int pair = prow0 + l15;
            const unsigned nb  = (unsigned)(lg * 16 + ks * 64);
            const unsigned off = (unsigned)pair * 128u + (nb ^ ((unsigned)(pair & 7) << 4));
            af[ks] = __builtin_bit_cast(f16x8, *(const bf16x8*)((const char*)coef + off));
        }

        f32x4 acc[8];
        #pragma unroll
        for (int nt = 0; nt < 8; ++nt) acc[nt] = (f32x4){0.f, 0.f, 0.f, 0.f};
        #pragma unroll
        for (int ks = 0; ks < 2; ++ks)
            #pragma unroll
            for (int nt = 0; nt < 8; ++nt)
                acc[nt] = __builtin_amdgcn_mfma_f32_16x16x32_f16(af[ks], bfrag[nt][ks], acc[nt], 0, 0, 0);

        // epilogue: PReLU, * W2[h], sum over this wave's 128 h
        float s[4] = {0.f, 0.f, 0.f, 0.f};
        #pragma unroll
        for (int nt = 0; nt < 8; ++nt)
            #pragma unroll
            for (int r = 0; r < 4; ++r) {
                float v = acc[nt][r];
                v = fmaxf(v, 0.f) + a * fminf(v, 0.f);
                s[r] += v * w2v[nt];
            }
        #pragma unroll
        for (int m = 1; m < 16; m <<= 1)
            #pragma unroll
            for (int r = 0; r < 4; ++r) s[r] += __shfl_xor(s[r], m);

        if (l15 == 0) {
            #pragma unroll
            for (int r = 0; r < 4; ++r)
                red[hh][ps * 128 + pt * 16 + lg * 4 + r] = s[r];
        }
    }
    __syncthreads();
    out[b * NPAIR + pairbase_blk + tid] = red[0][tid] + red[1][tid];
}

// ---------------------------------------------------------------------------
extern "C" void kernel_launch(void* const* d_in, const int* in_sizes, int n_in,
                              void* d_out, int out_size, void* d_ws, size_t ws_size,
                              hipStream_t stream) {
    const float* src     = (const float*)d_in[0];
    const float* W1      = (const float*)d_in[1];
    const float* W2      = (const float*)d_in[2];
    const float* prelu_a = (const float*)d_in[3];
    const int*   spd     = (const int*)d_in[4];
    const int*   spd_len = (const int*)d_in[5];
    float* out = (float*)d_out;

    unsigned short* yg   = (unsigned short*)d_ws;     // 1 MB (32 fp16 planes)
    unsigned short* coef = yg + 524288;               // 512 KB

    k1<<<512, 256, 0, stream>>>(src, W1, spd, spd_len, yg, coef);
    k2<<<512, 256, 0, stream>>>(yg, coef, W2, prelu_a, out);
}

// Round 5
// 26.462 us; speedup vs baseline: 5.5635x; 1.0694x over previous
//
#include <hip/hip_runtime.h>

// Shapes (fixed by the problem)
#define B_   32
#define N_   64
#define C_   256
#define H_   256
#define L_   16
#define NPAIR 4096
#define PPB   512            // pairs per block
#define PLANE_BYTES 32768    // [256h][64n] fp16 plane

typedef __attribute__((ext_vector_type(8))) short     bf16x8;
typedef __attribute__((ext_vector_type(8))) _Float16  f16x8;
typedef __attribute__((ext_vector_type(4))) float     f32x4;

static __device__ __forceinline__ unsigned short f2bf_rne(float f) {
    unsigned u = __builtin_bit_cast(unsigned, f);
    u += 0x7FFFu + ((u >> 16) & 1u);      // round-to-nearest-even
    return (unsigned short)(u >> 16);
}
static __device__ __forceinline__ float bf2f(unsigned short h) {
    unsigned u = ((unsigned)h) << 16;
    return __builtin_bit_cast(float, u);
}
static __device__ __forceinline__ unsigned short f2h(float f) {
    return __builtin_bit_cast(unsigned short, (_Float16)f);   // v_cvt_f16_f32 (RNE)
}

// ---------------------------------------------------------------------------
// Fused kernel. Grid 256 = (b:32) x (pg:8 groups of 512 pairs). 512 threads.
// LDS: srccoef 64KB (phase Y: src split-bf16 swizzled; phase C: coef fp16)
//      ylds    32KB (y[b] fp16, swizzled byte = h*128 + ((n*2)^((h&7)<<4)))
//      red     4KB
// ---------------------------------------------------------------------------
__global__ __launch_bounds__(512, 2)
void kFused(const float* __restrict__ src,
            const float* __restrict__ W1,
            const float* __restrict__ W2,
            const float* __restrict__ prelu_a,
            const int*   __restrict__ spd,
            const int*   __restrict__ spd_len,
            float*       __restrict__ out) {
    __shared__ char  srccoef[65536];
    __shared__ char  ylds[PLANE_BYTES];
    __shared__ float red[2][PPB];

    const int bid = blockIdx.x;
    const int b   = bid >> 3;
    const int pg  = bid & 7;
    const int tid = threadIdx.x;          // 0..511
    const int lane = tid & 63, w = tid >> 6;
    const int l15 = lane & 15, lg = lane >> 4;

    // ---- phase 0: stage src[b] -> LDS as split-bf16, swizzled [n][c]
    // hi plane at 0, lo plane at +32KB; row n = 512B; chunk16 XOR (n&7)<<4.
    {
        const float* sb = src + (size_t)b * (N_ * C_) + tid * 32;
        const int n  = tid >> 3;
        const int cc = (tid & 7) * 32;
        float4 q[8];
        #pragma unroll
        for (int i = 0; i < 8; ++i) q[i] = ((const float4*)sb)[i];
        #pragma unroll
        for (int m = 0; m < 4; ++m) {
            float v8[8] = {q[2*m].x, q[2*m].y, q[2*m].z, q[2*m].w,
                           q[2*m+1].x, q[2*m+1].y, q[2*m+1].z, q[2*m+1].w};
            unsigned hi[8], lo[8];
            #pragma unroll
            for (int j = 0; j < 8; ++j) {
                unsigned short hb = f2bf_rne(v8[j]);
                hi[j] = hb;
                lo[j] = f2bf_rne(v8[j] - bf2f(hb));
            }
            int4 vh, vl;
            vh.x = hi[0] | (hi[1] << 16); vh.y = hi[2] | (hi[3] << 16);
            vh.z = hi[4] | (hi[5] << 16); vh.w = hi[6] | (hi[7] << 16);
            vl.x = lo[0] | (lo[1] << 16); vl.y = lo[2] | (lo[3] << 16);
            vl.z = lo[4] | (lo[5] << 16); vl.w = lo[6] | (lo[7] << 16);
            const unsigned off = (unsigned)(n * 512) +
                (((unsigned)((cc + m * 8) * 2)) ^ ((unsigned)(n & 7) << 4));
            *(int4*)(srccoef + off)         = vh;
            *(int4*)(srccoef + 32768 + off) = vl;
        }
    }
    __syncthreads();

    // ---- phase Y: y[h][n] = sum_c W1[h][c]*src[n][c], 3-pass split-bf16.
    // Wave w -> h-octant [w*32, +32). A = src (rows n, from LDS), B = W1
    // (cols h, fp32 from global, split in-register). D: col=h(l15), row=n.
    {
        const int hbase = w * 32;
        f32x4 acc[2][4];
        #pragma unroll
        for (int ht = 0; ht < 2; ++ht)
            #pragma unroll
            for (int nt = 0; nt < 4; ++nt) acc[ht][nt] = (f32x4){0.f,0.f,0.f,0.f};

        #pragma unroll
        for (int kc = 0; kc < 8; ++kc) {
            bf16x8 sah[4], sal[4];
            #pragma unroll
            for (int nt = 0; nt < 4; ++nt) {
                const int n = nt * 16 + l15;
                const unsigned off = (unsigned)(n * 512) +
                    (((unsigned)(kc * 64 + lg * 16)) ^ ((unsigned)(n & 7) << 4));
                sah[nt] = *(const bf16x8*)(srccoef + off);
                sal[nt] = *(const bf16x8*)(srccoef + 32768 + off);
            }
            #pragma unroll
            for (int ht = 0; ht < 2; ++ht) {
                const int h = hbase + ht * 16 + l15;
                const float* wp = W1 + h * C_ + kc * 32 + lg * 8;
                float4 q0 = *(const float4*)wp;
                float4 q1 = *(const float4*)(wp + 4);
                float v8[8] = {q0.x,q0.y,q0.z,q0.w,q1.x,q1.y,q1.z,q1.w};
                bf16x8 wh, wl;
                #pragma unroll
                for (int j = 0; j < 8; ++j) {
                    unsigned short hb = f2bf_rne(v8[j]);
                    wh[j] = (short)hb;
                    wl[j] = (short)f2bf_rne(v8[j] - bf2f(hb));
                }
                #pragma unroll
                for (int nt = 0; nt < 4; ++nt) {
                    acc[ht][nt] = __builtin_amdgcn_mfma_f32_16x16x32_bf16(sah[nt], wh, acc[ht][nt], 0, 0, 0);
                    acc[ht][nt] = __builtin_amdgcn_mfma_f32_16x16x32_bf16(sah[nt], wl, acc[ht][nt], 0, 0, 0);
                    acc[ht][nt] = __builtin_amdgcn_mfma_f32_16x16x32_bf16(sal[nt], wh, acc[ht][nt], 0, 0, 0);
                }
            }
        }

        // write y tiles: lane has 4 consecutive n (rows) at fixed h (col)
        #pragma unroll
        for (int ht = 0; ht < 2; ++ht) {
            const int h = hbase + ht * 16 + l15;
            #pragma unroll
            for (int nt = 0; nt < 4; ++nt) {
                const int n0 = nt * 16 + lg * 4;
                unsigned pk[2];
                pk[0] = (unsigned)f2h(acc[ht][nt][0]) | ((unsigned)f2h(acc[ht][nt][1]) << 16);
                pk[1] = (unsigned)f2h(acc[ht][nt][2]) | ((unsigned)f2h(acc[ht][nt][3]) << 16);
                const unsigned off = (unsigned)(h * 128) +
                    (((unsigned)(n0 * 2)) ^ ((unsigned)(h & 7) << 4));
                *(int2*)(ylds + off) = *(int2*)pk;
            }
        }
    }
    __syncthreads();

    // ---- coef build: fp16 rows (128B/pair, swizzled) into srccoef.
    // Conflict-free zeroing (contiguous 1KB per lane-step), then
    // thread t owns local pair t: sequential +-1 RMW on its own row.
    {
        const int4 z = {0, 0, 0, 0};
        #pragma unroll
        for (int i = 0; i < 8; ++i)
            *(int4*)(srccoef + tid * 16 + i * 8192) = z;
    }
    __syncthreads();
    {
        const int gp  = pg * PPB + tid;          // global pair
        const int len = spd_len[gp];
        const int* row = spd + gp * L_;
        char* myrow = srccoef + tid * 128;
        const unsigned swz = (unsigned)(tid & 7) << 4;
        int h0 = row[0];
        for (int k = 1; k < len; ++k) {
            const int e = row[k];
            _Float16* pe = (_Float16*)(myrow + (((unsigned)(e  * 2)) ^ swz));
            *pe = *pe + (_Float16)1;
            _Float16* ph = (_Float16*)(myrow + (((unsigned)(h0 * 2)) ^ swz));
            *ph = *ph - (_Float16)1;
            h0 = e;
        }
    }
    __syncthreads();

    // ---- phase C: h = coef * y, PReLU, W2-dot. 8 waves: ps=w>>1 (128 pairs),
    // hh=w&1 (128 h). Persistent y B-frags; A-frags from coef LDS.
    {
        const int ps = w >> 1, hh = w & 1;

        f16x8 bfrag[8][2];
        #pragma unroll
        for (int nt = 0; nt < 8; ++nt) {
            const int h = hh * 128 + nt * 16 + l15;
            #pragma unroll
            for (int ks = 0; ks < 2; ++ks) {
                const unsigned nb  = (unsigned)(lg * 16 + ks * 64);
                const unsigned off = (unsigned)(h * 128) + (nb ^ ((unsigned)(h & 7) << 4));
                bfrag[nt][ks] = *(const f16x8*)(ylds + off);
            }
        }

        float w2v[8];
        #pragma unroll
        for (int nt = 0; nt < 8; ++nt) w2v[nt] = W2[hh * 128 + nt * 16 + l15];
        const float a = *prelu_a;

        for (int pt = 0; pt < 8; ++pt) {
            const int prow0 = ps * 128 + pt * 16;       // local pair base
            const int pl    = prow0 + l15;

            f16x8 af[2];
            #pragma unroll
            for (int ks = 0; ks < 2; ++ks) {
                const unsigned nb  = (unsigned)(lg * 16 + ks * 64);
                const unsigned off = (unsigned)(pl * 128) + (nb ^ ((unsigned)(pl & 7) << 4));
                af[ks] = *(const f16x8*)(srccoef + off);
            }

            f32x4 acc[8];
            #pragma unroll
            for (int nt = 0; nt < 8; ++nt) acc[nt] = (f32x4){0.f,0.f,0.f,0.f};
            #pragma unroll
            for (int ks = 0; ks < 2; ++ks)
                #pragma unroll
                for (int nt = 0; nt < 8; ++nt)
                    acc[nt] = __builtin_amdgcn_mfma_f32_16x16x32_f16(af[ks], bfrag[nt][ks], acc[nt], 0, 0, 0);

            float s[4] = {0.f, 0.f, 0.f, 0.f};
            #pragma unroll
            for (int nt = 0; nt < 8; ++nt)
                #pragma unroll
                for (int r = 0; r < 4; ++r) {
                    float v = acc[nt][r];
                    v = fmaxf(v, 0.f) + a * fminf(v, 0.f);
                    s[r] += v * w2v[nt];
                }
            #pragma unroll
            for (int m = 1; m < 16; m <<= 1)
                #pragma unroll
                for (int r = 0; r < 4; ++r) s[r] += __shfl_xor(s[r], m);

            if (l15 == 0) {
                #pragma unroll
                for (int r = 0; r < 4; ++r)
                    red[hh][prow0 + lg * 4 + r] = s[r];
            }
        }
    }
    __syncthreads();
    out[b * NPAIR + pg * PPB + tid] = red[0][tid] + red[1][tid];
}

// ---------------------------------------------------------------------------
extern "C" void kernel_launch(void* const* d_in, const int* in_sizes, int n_in,
                              void* d_out, int out_size, void* d_ws, size_t ws_size,
                              hipStream_t stream) {
    const float* src     = (const float*)d_in[0];
    const float* W1      = (const float*)d_in[1];
    const float* W2      = (const float*)d_in[2];
    const float* prelu_a = (const float*)d_in[3];
    const int*   spd     = (const int*)d_in[4];
    const int*   spd_len = (const int*)d_in[5];
    float* out = (float*)d_out;

    kFused<<<256, 512, 0, stream>>>(src, W1, W2, prelu_a, spd, spd_len, out);
}